// Round 2
// baseline (5525.336 us; speedup 1.0000x reference)
//
#include <hip/hip_runtime.h>
#include <hip/hip_bf16.h>
#include <math.h>

// ---------------------------------------------------------------------------
// WindowMoBA, reduced form:
//   out_pre[m,h,n,:] = 0.25 * sum_{tt<4} softmax(SCALE*q[tt*128+m/4,h] K[m%32,h]^T + bias_h) V[m%32,h]
//   out = out_pre @ w_proj + b_proj
// Gate/topk are dead code. K/V needed only for rows 0..1567 (kv groups 0..31).
// ---------------------------------------------------------------------------

#define N_TOK   49
#define DIMC    256
#define HEADS   8
#define HEAD_D  32
#define BWIN    512                  // B_ = BATCH*NUM_WIN
#define NKV     32                   // distinct K/V groups
#define MROWS   (BWIN * N_TOK)       // 25088
#define KVROWS  (NKV * N_TOK)        // 1568
// SCALE * log2(e): softmax done in exp2 domain (native v_exp_f32)
#define SCALE_L2 (0.17677669529663687f * 1.4426950408889634f)
#define LOG2E    1.4426950408889634f

// ---------------------------------------------------------------------------
// fp32 GEMM tile (unchanged from round 1): C = A[Mx256] @ W + bias
// ---------------------------------------------------------------------------
__device__ __forceinline__ void gemm_tile_128(
    const float* __restrict__ A, int M,
    const float* __restrict__ W, int ldw, int wcol0,
    const float* __restrict__ bias,
    float* __restrict__ C, int ldc,
    int mt, int nt, float* As /* 128*32 floats */)
{
    const int tid = threadIdx.x;
    const int tr  = tid >> 4;
    const int tc  = tid & 15;
    const int R0  = mt * 128;
    const int C0  = nt * 128;
    const int wc0 = wcol0 + C0 + tc * 8;

    float acc[8][8];
    #pragma unroll
    for (int j = 0; j < 8; ++j) {
        float bj = bias[wc0 + j];
        #pragma unroll
        for (int i = 0; i < 8; ++i) acc[i][j] = bj;
    }

    for (int kc = 0; kc < 8; ++kc) {
        if (kc) __syncthreads();
        #pragma unroll
        for (int it = 0; it < 4; ++it) {
            int flat = it * 256 + tid;
            int row  = flat >> 3;
            int q8   = flat & 7;
            int gr   = R0 + row; if (gr > M - 1) gr = M - 1;
            float4 v = *(const float4*)(A + (size_t)gr * 256 + kc * 32 + q8 * 4);
            int q8s  = q8 ^ ((row >> 3) & 7);
            *(float4*)(As + row * 32 + q8s * 4) = v;
        }
        __syncthreads();

        #pragma unroll
        for (int kk4 = 0; kk4 < 8; ++kk4) {
            float a[8][4];
            const int cg = (kk4 ^ (tr & 7)) << 2;
            #pragma unroll
            for (int i = 0; i < 8; ++i) {
                float4 t = *(const float4*)(As + (tr * 8 + i) * 32 + cg);
                a[i][0] = t.x; a[i][1] = t.y; a[i][2] = t.z; a[i][3] = t.w;
            }
            #pragma unroll
            for (int dk = 0; dk < 4; ++dk) {
                const float* wp = W + (size_t)(kc * 32 + kk4 * 4 + dk) * ldw + wc0;
                float4 w0 = *(const float4*)(wp);
                float4 w1 = *(const float4*)(wp + 4);
                float wv[8] = {w0.x, w0.y, w0.z, w0.w, w1.x, w1.y, w1.z, w1.w};
                #pragma unroll
                for (int i = 0; i < 8; ++i) {
                    float av = a[i][dk];
                    #pragma unroll
                    for (int j = 0; j < 8; ++j)
                        acc[i][j] = fmaf(av, wv[j], acc[i][j]);
                }
            }
        }
    }

    #pragma unroll
    for (int i = 0; i < 8; ++i) {
        int gr = R0 + tr * 8 + i;
        if (gr < M) {
            float* cp = C + (size_t)gr * ldc + C0 + tc * 8;
            float4 s0 = {acc[i][0], acc[i][1], acc[i][2], acc[i][3]};
            float4 s1 = {acc[i][4], acc[i][5], acc[i][6], acc[i][7]};
            *(float4*)(cp)     = s0;
            *(float4*)(cp + 4) = s1;
        }
    }
}

__global__ __launch_bounds__(256) void k_gemm_qkv(
    const float* __restrict__ x, const float* __restrict__ w,
    const float* __restrict__ b, float* __restrict__ qbuf,
    float* __restrict__ kvbuf)
{
    __shared__ float As[128 * 32];
    int bx = blockIdx.x;
    if (bx < 392) {
        gemm_tile_128(x, MROWS, w, 768, 0,   b, qbuf,  256, bx >> 1, bx & 1, As);
    } else {
        int b2 = bx - 392;
        gemm_tile_128(x, KVROWS, w, 768, 256, b, kvbuf, 512, b2 >> 2, b2 & 3, As);
    }
}

__global__ __launch_bounds__(256) void k_gemm_proj(
    const float* __restrict__ ob, const float* __restrict__ w,
    const float* __restrict__ b, float* __restrict__ out)
{
    __shared__ float As[128 * 32];
    gemm_tile_128(ob, MROWS, w, 256, 0, b, out, 256, blockIdx.x >> 1, blockIdx.x & 1, As);
}

// ---------------------------------------------------------------------------
// Attention v2: block = (kv, h, wgroup). K/V/bias staged in LDS once, shared
// by the 16 outputs m = kv + 32*w. 4 waves/block, wave wi owns w = wg*4+wi
// and accumulates all 4 tt in registers. Per-lane state ~113 floats (no
// spill; bias lives in LDS, pre-scaled by log2e for exp2-domain softmax).
// ---------------------------------------------------------------------------
__global__ __launch_bounds__(256) void k_attn(
    const float* __restrict__ qbuf,   // (25088, 256)
    const float* __restrict__ kvbuf,  // (1568, 512): cols 0..255 K, 256..511 V
    const float* __restrict__ table,  // (169, 8)
    float* __restrict__ obuf)         // (25088, 256)
{
    __shared__ float Ks[49 * 32];
    __shared__ float Vs[49 * 32];
    __shared__ float Bs[49 * 49];

    const int kv  = blockIdx.x;   // 0..31
    const int h   = blockIdx.y;   // 0..7
    const int wg  = blockIdx.z;   // 0..3
    const int tid = threadIdx.x;

    // ---- stage K/V head slices (49 x 32 each)
    const float* kvb = kvbuf + (size_t)(kv * 49) * 512 + h * 32;
    for (int idx = tid; idx < 392; idx += 256) {
        int row = idx >> 3, q4 = idx & 7;
        const float* src = kvb + row * 512 + q4 * 4;
        ((float4*)Ks)[idx] = *(const float4*)src;
        ((float4*)Vs)[idx] = *(const float4*)(src + 256);
    }
    // ---- stage bias row-major (49 x 49), pre-scaled by log2(e)
    for (int idx = tid; idx < 2401; idx += 256) {
        int r = idx / 49, j = idx - r * 49;
        int rh = r / 7, rw = r - rh * 7;
        int jh = j / 7, jw = j - jh * 7;
        int t = ((rh - jh + 6) * 13 + (rw - jw + 6)) * HEADS + h;
        Bs[idx] = table[t] * LOG2E;
    }
    __syncthreads();

    const int lane = tid & 63;
    const int wi   = tid >> 6;
    const int w    = wg * 4 + wi;        // 0..15
    const int m    = kv + 32 * w;        // 0..511
    const int r    = lane < 49 ? lane : 48;

    float o[32];
    #pragma unroll
    for (int d = 0; d < 32; ++d) o[d] = 0.f;

    for (int tt = 0; tt < 4; ++tt) {
        const int qidx = tt * 128 + (m >> 2);
        const float* qp = qbuf + ((size_t)qidx * 49 + r) * 256 + h * 32;
        float q[32];
        #pragma unroll
        for (int d4 = 0; d4 < 8; ++d4) {
            float4 t4 = *(const float4*)(qp + d4 * 4);
            q[d4*4+0] = t4.x * SCALE_L2; q[d4*4+1] = t4.y * SCALE_L2;
            q[d4*4+2] = t4.z * SCALE_L2; q[d4*4+3] = t4.w * SCALE_L2;
        }

        float s[49];
        #pragma unroll
        for (int j = 0; j < 49; ++j) {
            const float* kp = Ks + j * 32;        // wave-uniform -> LDS broadcast
            float a0 = 0.f, a1 = 0.f, a2 = 0.f, a3 = 0.f;
            #pragma unroll
            for (int d4 = 0; d4 < 8; ++d4) {
                float4 k4 = *(const float4*)(kp + d4 * 4);
                a0 = fmaf(q[d4*4+0], k4.x, a0);
                a1 = fmaf(q[d4*4+1], k4.y, a1);
                a2 = fmaf(q[d4*4+2], k4.z, a2);
                a3 = fmaf(q[d4*4+3], k4.w, a3);
            }
            s[j] = (a0 + a1) + (a2 + a3) + Bs[r * 49 + j];
        }

        // in-lane softmax (exp2 domain)
        float mx = s[0];
        #pragma unroll
        for (int j = 1; j < 49; ++j) mx = fmaxf(mx, s[j]);
        float sum = 0.f;
        #pragma unroll
        for (int j = 0; j < 49; ++j) { s[j] = exp2f(s[j] - mx); sum += s[j]; }
        const float inv = 1.0f / sum;
        #pragma unroll
        for (int j = 0; j < 49; ++j) s[j] *= inv;

        // PV from LDS (broadcast reads)
        #pragma unroll
        for (int j = 0; j < 49; ++j) {
            const float* vp = Vs + j * 32;
            const float pj = s[j];
            #pragma unroll
            for (int d4 = 0; d4 < 8; ++d4) {
                float4 v4 = *(const float4*)(vp + d4 * 4);
                o[d4*4+0] = fmaf(pj, v4.x, o[d4*4+0]);
                o[d4*4+1] = fmaf(pj, v4.y, o[d4*4+1]);
                o[d4*4+2] = fmaf(pj, v4.z, o[d4*4+2]);
                o[d4*4+3] = fmaf(pj, v4.w, o[d4*4+3]);
            }
        }
    }

    if (lane < 49) {
        float* op = obuf + ((size_t)m * 49 + lane) * 256 + h * 32;
        #pragma unroll
        for (int d4 = 0; d4 < 8; ++d4) {
            float4 t = {o[d4*4+0] * 0.25f, o[d4*4+1] * 0.25f,
                        o[d4*4+2] * 0.25f, o[d4*4+3] * 0.25f};
            *(float4*)(op + d4 * 4) = t;
        }
    }
}

// ---------------------------------------------------------------------------
extern "C" void kernel_launch(void* const* d_in, const int* in_sizes, int n_in,
                              void* d_out, int out_size, void* d_ws, size_t ws_size,
                              hipStream_t stream)
{
    const float* x      = (const float*)d_in[0];
    const float* w_qkv  = (const float*)d_in[1];
    const float* b_qkv  = (const float*)d_in[2];
    const float* table  = (const float*)d_in[3];
    const float* w_proj = (const float*)d_in[4];
    const float* b_proj = (const float*)d_in[5];
    float* out = (float*)d_out;

    float* qbuf  = (float*)d_ws;
    float* kvbuf = qbuf + (size_t)MROWS * 256;
    float* obuf  = kvbuf + (size_t)KVROWS * 512;

    k_gemm_qkv<<<444, 256, 0, stream>>>(x, w_qkv, b_qkv, qbuf, kvbuf);
    k_attn<<<dim3(32, 8, 4), 256, 0, stream>>>(qbuf, kvbuf, table, obuf);
    k_gemm_proj<<<392, 256, 0, stream>>>(obuf, w_proj, b_proj, out);
}

// Round 4
// 341.059 us; speedup vs baseline: 16.2005x; 16.2005x over previous
//
#include <hip/hip_runtime.h>
#include <hip/hip_bf16.h>
#include <math.h>

// ---------------------------------------------------------------------------
// WindowMoBA, reduced form:
//   out_pre[m,h,n,:] = 0.25 * sum_{tt<4} softmax(SCALE*q[tt*128+m/4,h] K[m%32,h]^T + bias_h) V[m%32,h]
//   out = out_pre @ w_proj + b_proj
// Gate/topk are dead code. K/V needed only for rows 0..1567 (kv groups 0..31).
// ---------------------------------------------------------------------------

#define N_TOK   49
#define DIMC    256
#define HEADS   8
#define HEAD_D  32
#define BWIN    512                  // B_ = BATCH*NUM_WIN
#define NKV     32                   // distinct K/V groups
#define MROWS   (BWIN * N_TOK)       // 25088
#define KVROWS  (NKV * N_TOK)        // 1568
// softmax in exp2 domain (native v_exp_f32): fold SCALE*log2(e) into q,
// log2(e) into bias.
#define SCALE_L2 (0.17677669529663687f * 1.4426950408889634f)
#define LOG2E    1.4426950408889634f

// ---------------------------------------------------------------------------
// fp32 GEMM tile (unchanged): C = A[Mx256] @ W + bias
// ---------------------------------------------------------------------------
__device__ __forceinline__ void gemm_tile_128(
    const float* __restrict__ A, int M,
    const float* __restrict__ W, int ldw, int wcol0,
    const float* __restrict__ bias,
    float* __restrict__ C, int ldc,
    int mt, int nt, float* As /* 128*32 floats */)
{
    const int tid = threadIdx.x;
    const int tr  = tid >> 4;
    const int tc  = tid & 15;
    const int R0  = mt * 128;
    const int C0  = nt * 128;
    const int wc0 = wcol0 + C0 + tc * 8;

    float acc[8][8];
    #pragma unroll
    for (int j = 0; j < 8; ++j) {
        float bj = bias[wc0 + j];
        #pragma unroll
        for (int i = 0; i < 8; ++i) acc[i][j] = bj;
    }

    for (int kc = 0; kc < 8; ++kc) {
        if (kc) __syncthreads();
        #pragma unroll
        for (int it = 0; it < 4; ++it) {
            int flat = it * 256 + tid;
            int row  = flat >> 3;
            int q8   = flat & 7;
            int gr   = R0 + row; if (gr > M - 1) gr = M - 1;
            float4 v = *(const float4*)(A + (size_t)gr * 256 + kc * 32 + q8 * 4);
            int q8s  = q8 ^ ((row >> 3) & 7);
            *(float4*)(As + row * 32 + q8s * 4) = v;
        }
        __syncthreads();

        #pragma unroll
        for (int kk4 = 0; kk4 < 8; ++kk4) {
            float a[8][4];
            const int cg = (kk4 ^ (tr & 7)) << 2;
            #pragma unroll
            for (int i = 0; i < 8; ++i) {
                float4 t = *(const float4*)(As + (tr * 8 + i) * 32 + cg);
                a[i][0] = t.x; a[i][1] = t.y; a[i][2] = t.z; a[i][3] = t.w;
            }
            #pragma unroll
            for (int dk = 0; dk < 4; ++dk) {
                const float* wp = W + (size_t)(kc * 32 + kk4 * 4 + dk) * ldw + wc0;
                float4 w0 = *(const float4*)(wp);
                float4 w1 = *(const float4*)(wp + 4);
                float wv[8] = {w0.x, w0.y, w0.z, w0.w, w1.x, w1.y, w1.z, w1.w};
                #pragma unroll
                for (int i = 0; i < 8; ++i) {
                    float av = a[i][dk];
                    #pragma unroll
                    for (int j = 0; j < 8; ++j)
                        acc[i][j] = fmaf(av, wv[j], acc[i][j]);
                }
            }
        }
    }

    #pragma unroll
    for (int i = 0; i < 8; ++i) {
        int gr = R0 + tr * 8 + i;
        if (gr < M) {
            float* cp = C + (size_t)gr * ldc + C0 + tc * 8;
            float4 s0 = {acc[i][0], acc[i][1], acc[i][2], acc[i][3]};
            float4 s1 = {acc[i][4], acc[i][5], acc[i][6], acc[i][7]};
            *(float4*)(cp)     = s0;
            *(float4*)(cp + 4) = s1;
        }
    }
}

__global__ __launch_bounds__(256) void k_gemm_qkv(
    const float* __restrict__ x, const float* __restrict__ w,
    const float* __restrict__ b, float* __restrict__ qbuf,
    float* __restrict__ kvbuf)
{
    __shared__ float As[128 * 32];
    int bx = blockIdx.x;
    if (bx < 392) {
        gemm_tile_128(x, MROWS, w, 768, 0,   b, qbuf,  256, bx >> 1, bx & 1, As);
    } else {
        int b2 = bx - 392;
        gemm_tile_128(x, KVROWS, w, 768, 256, b, kvbuf, 512, b2 >> 2, b2 & 3, As);
    }
}

__global__ __launch_bounds__(256) void k_gemm_proj(
    const float* __restrict__ ob, const float* __restrict__ w,
    const float* __restrict__ b, float* __restrict__ out)
{
    __shared__ float As[128 * 32];
    gemm_tile_128(ob, MROWS, w, 256, 0, b, out, 256, blockIdx.x >> 1, blockIdx.x & 1, As);
}

// ---------------------------------------------------------------------------
// Attention v3: same (kv,h,wg) LDS-sharing structure as v2, but register-lean:
// streaming softmax WITHOUT max subtraction (scores ~N(0,1)+bias, exp2 args
// bounded; softmax is shift-invariant so this is exact math). No s[49] array:
// per j, e = exp2(q.k_j + bias) -> sum += e, o_tt += e*v_j. Live state
// q[32]+o_tt[32]+o_tot[32]+sum ~ 100 regs; __launch_bounds__(256,4) caps at
// 128 VGPR (fits, no spill). Round-2 lesson: s[49] live across unrolled
// LDS-read loops -> 256 VGPR + 11.5 GB scratch->HBM. Never again.
// ---------------------------------------------------------------------------
__global__ __launch_bounds__(256, 4) void k_attn(
    const float* __restrict__ qbuf,   // (25088, 256)
    const float* __restrict__ kvbuf,  // (1568, 512): cols 0..255 K, 256..511 V
    const float* __restrict__ table,  // (169, 8)
    float* __restrict__ obuf)         // (25088, 256)
{
    __shared__ float Ks[49 * 32];
    __shared__ float Vs[49 * 32];
    __shared__ float Bs[49 * 49];

    const int kv  = blockIdx.x;   // 0..31
    const int h   = blockIdx.y;   // 0..7
    const int wg  = blockIdx.z;   // 0..3
    const int tid = threadIdx.x;

    // ---- stage K/V head slices (49 x 32 each)
    const float* kvb = kvbuf + (size_t)(kv * 49) * 512 + h * 32;
    for (int idx = tid; idx < 392; idx += 256) {
        int row = idx >> 3, q4 = idx & 7;
        const float* src = kvb + row * 512 + q4 * 4;
        ((float4*)Ks)[idx] = *(const float4*)src;
        ((float4*)Vs)[idx] = *(const float4*)(src + 256);
    }
    // ---- stage bias (49 x 49), pre-scaled by log2(e)
    for (int idx = tid; idx < 2401; idx += 256) {
        int r = idx / 49, j = idx - r * 49;
        int rh = r / 7, rw = r - rh * 7;
        int jh = j / 7, jw = j - jh * 7;
        int t = ((rh - jh + 6) * 13 + (rw - jw + 6)) * HEADS + h;
        Bs[idx] = table[t] * LOG2E;
    }
    __syncthreads();

    const int lane = tid & 63;
    const int wi   = tid >> 6;
    const int w    = wg * 4 + wi;        // 0..15
    const int m    = kv + 32 * w;        // 0..511
    const int r    = lane < 49 ? lane : 48;
    const float* brow = Bs + r * 49;

    float o_tot[32];
    #pragma unroll
    for (int d = 0; d < 32; ++d) o_tot[d] = 0.f;

    for (int tt = 0; tt < 4; ++tt) {
        const int qidx = tt * 128 + (m >> 2);
        const float* qp = qbuf + ((size_t)qidx * 49 + r) * 256 + h * 32;
        float q[32];
        #pragma unroll
        for (int d4 = 0; d4 < 8; ++d4) {
            float4 t4 = *(const float4*)(qp + d4 * 4);
            q[d4*4+0] = t4.x * SCALE_L2; q[d4*4+1] = t4.y * SCALE_L2;
            q[d4*4+2] = t4.z * SCALE_L2; q[d4*4+3] = t4.w * SCALE_L2;
        }

        float o_tt[32];
        #pragma unroll
        for (int d = 0; d < 32; ++d) o_tt[d] = 0.f;
        float sum = 0.f;

        #pragma unroll 7
        for (int j = 0; j < 49; ++j) {
            const float* kp = Ks + j * 32;        // wave-uniform LDS broadcast
            float a0 = 0.f, a1 = 0.f, a2 = 0.f, a3 = 0.f;
            #pragma unroll
            for (int d4 = 0; d4 < 8; ++d4) {
                float4 k4 = *(const float4*)(kp + d4 * 4);
                a0 = fmaf(q[d4*4+0], k4.x, a0);
                a1 = fmaf(q[d4*4+1], k4.y, a1);
                a2 = fmaf(q[d4*4+2], k4.z, a2);
                a3 = fmaf(q[d4*4+3], k4.w, a3);
            }
            const float e = exp2f((a0 + a1) + (a2 + a3) + brow[j]);
            sum += e;

            const float* vp = Vs + j * 32;        // wave-uniform LDS broadcast
            #pragma unroll
            for (int d4 = 0; d4 < 8; ++d4) {
                float4 v4 = *(const float4*)(vp + d4 * 4);
                o_tt[d4*4+0] = fmaf(e, v4.x, o_tt[d4*4+0]);
                o_tt[d4*4+1] = fmaf(e, v4.y, o_tt[d4*4+1]);
                o_tt[d4*4+2] = fmaf(e, v4.z, o_tt[d4*4+2]);
                o_tt[d4*4+3] = fmaf(e, v4.w, o_tt[d4*4+3]);
            }
        }

        const float inv = 1.0f / sum;
        #pragma unroll
        for (int d = 0; d < 32; ++d) o_tot[d] = fmaf(o_tt[d], inv, o_tot[d]);
    }

    if (lane < 49) {
        float* op = obuf + ((size_t)m * 49 + lane) * 256 + h * 32;
        #pragma unroll
        for (int d4 = 0; d4 < 8; ++d4) {
            float4 t = {o_tot[d4*4+0] * 0.25f, o_tot[d4*4+1] * 0.25f,
                        o_tot[d4*4+2] * 0.25f, o_tot[d4*4+3] * 0.25f};
            *(float4*)(op + d4 * 4) = t;
        }
    }
}

// ---------------------------------------------------------------------------
extern "C" void kernel_launch(void* const* d_in, const int* in_sizes, int n_in,
                              void* d_out, int out_size, void* d_ws, size_t ws_size,
                              hipStream_t stream)
{
    const float* x      = (const float*)d_in[0];
    const float* w_qkv  = (const float*)d_in[1];
    const float* b_qkv  = (const float*)d_in[2];
    const float* table  = (const float*)d_in[3];
    const float* w_proj = (const float*)d_in[4];
    const float* b_proj = (const float*)d_in[5];
    float* out = (float*)d_out;

    float* qbuf  = (float*)d_ws;
    float* kvbuf = qbuf + (size_t)MROWS * 256;
    float* obuf  = kvbuf + (size_t)KVROWS * 512;

    k_gemm_qkv<<<444, 256, 0, stream>>>(x, w_qkv, b_qkv, qbuf, kvbuf);
    k_attn<<<dim3(32, 8, 4), 256, 0, stream>>>(qbuf, kvbuf, table, obuf);
    k_gemm_proj<<<392, 256, 0, stream>>>(obuf, w_proj, b_proj, out);
}

// Round 13
// 275.608 us; speedup vs baseline: 20.0478x; 1.2375x over previous
//
#include <hip/hip_runtime.h>
#include <hip/hip_bf16.h>
#include <math.h>

// ---------------------------------------------------------------------------
// WindowMoBA, reduced form:
//   out_pre[m,h,n,:] = 0.25 * sum_{tt<4} softmax(SCALE*q[tt*128+m/4,h] K[m%32,h]^T + bias_h) V[m%32,h]
//   out = out_pre @ w_proj + b_proj
// Gate/topk are dead code. K/V needed only for rows 0..1567 (kv groups 0..31).
//
// Pipeline: k_prep (cast x->bf16, transpose-cast W's)
//        -> k_gemm_qkv (bf16 MFMA: Q->qbuf bf16, K/V->kvbuf f32)
//        -> k_attn (fp32 VALU, LDS K/V/bias; writes obuf bf16)
//        -> k_gemm_proj (bf16 MFMA -> f32 out)
// ---------------------------------------------------------------------------

#define N_TOK   49
#define HEADS   8
#define MROWS   25088                // 512*49
#define KVROWS  1568                 // 32*49
#define SCALE_L2 (0.17677669529663687f * 1.4426950408889634f)
#define LOG2E    1.4426950408889634f

using bf16x8 = __attribute__((ext_vector_type(8))) short;
using f32x4  = __attribute__((ext_vector_type(4))) float;

__device__ __forceinline__ ushort f2b(float f) {
    __hip_bfloat16 h = __float2bfloat16(f);
    ushort u; __builtin_memcpy(&u, &h, 2); return u;
}

// ---------------------------------------------------------------------------
// prep: [0,6272) x float4->bf16x4 | [6272,7040) w_qkv^T | [7040,7296) w_proj^T
// W^T layout: [n][k] bf16, k contiguous (both MFMA operands want 8-contig-k).
// ---------------------------------------------------------------------------
__global__ __launch_bounds__(256) void k_prep(
    const float* __restrict__ x, const float* __restrict__ wq,
    const float* __restrict__ wp, ushort* __restrict__ xb,
    ushort* __restrict__ wqT, ushort* __restrict__ wpT)
{
    int bx = blockIdx.x, tid = threadIdx.x;
    if (bx < 6272) {
        int i = bx * 256 + tid;                      // 1605632 float4's
        float4 v = ((const float4*)x)[i];
        ushort4 o = {f2b(v.x), f2b(v.y), f2b(v.z), f2b(v.w)};
        *(ushort4*)(xb + 4 * (size_t)i) = o;
    } else if (bx < 7040) {
        int j = (bx - 6272) * 256 + tid;             // 196608: n=j>>8, k=j&255
        int n = j >> 8, k = j & 255;
        wqT[j] = f2b(wq[(size_t)k * 768 + n]);
    } else {
        int j = (bx - 7040) * 256 + tid;             // 65536
        int n = j >> 8, k = j & 255;
        wpT[j] = f2b(wp[(size_t)k * 256 + n]);
    }
}

// ---------------------------------------------------------------------------
// bf16 MFMA GEMM tile: C[128x128] = A[M x 256]_bf16 @ W^T[N][256]_bf16 + bias
// 256 thr = 4 waves (2x2 of 64x64). BK=64, 4 k-chunks, single-buffer LDS.
// Staging: global_load_lds width16, linear LDS dest + PRE-SWIZZLED global
// source (slot' = slot ^ (row&7)); frag ds_read_b128 applies the same XOR
// -> 2-way max bank conflict (free). MODE: 0=bf16 out ldc256, 1=f32 out
// ldc512 col-256 rowguard (KV), 2=f32 out ldc256 (proj).
// ---------------------------------------------------------------------------
template<int MODE>
__device__ __forceinline__ void mfma_tile(
    const ushort* __restrict__ Ab, int M,
    const ushort* __restrict__ WT,
    const float* __restrict__ bias,
    void* __restrict__ Cout,
    int R0, int NT0, ushort* As, ushort* Bs)
{
    const int tid = threadIdx.x;
    const int wid = tid >> 6, lane = tid & 63;
    const int wr = wid >> 1, wc = wid & 1;
    const int l15 = lane & 15, kg = lane >> 4;

    f32x4 acc[4][4];
    #pragma unroll
    for (int mi = 0; mi < 4; ++mi)
        #pragma unroll
        for (int ni = 0; ni < 4; ++ni)
            acc[mi][ni] = (f32x4){0.f, 0.f, 0.f, 0.f};

    for (int kc = 0; kc < 4; ++kc) {
        if (kc) __syncthreads();
        #pragma unroll
        for (int it = 0; it < 4; ++it) {
            int f    = it * 256 + tid;               // 16B chunk id
            int row  = f >> 3, slot = f & 7;
            int sl   = slot ^ (row & 7);             // pre-swizzle source
            char* dst = (char*)As + (size_t)it * 4096 + wid * 1024; // wave-uniform
            int ga   = R0 + row; if (ga > M - 1) ga = M - 1;
            __builtin_amdgcn_global_load_lds(
                (const void*)(Ab + (size_t)ga * 256 + kc * 64 + sl * 8),
                (void*)dst, 16, 0, 0);
            char* dstB = (char*)Bs + (size_t)it * 4096 + wid * 1024;
            __builtin_amdgcn_global_load_lds(
                (const void*)(WT + (size_t)(NT0 + row) * 256 + kc * 64 + sl * 8),
                (void*)dstB, 16, 0, 0);
        }
        __syncthreads();

        #pragma unroll
        for (int ks = 0; ks < 2; ++ks) {
            bf16x8 af[4], bfr[4];
            #pragma unroll
            for (int t = 0; t < 4; ++t) {
                int arow = wr * 64 + t * 16 + l15;
                int aslt = (ks * 4 + kg) ^ (arow & 7);
                af[t]  = *(const bf16x8*)((const char*)As + arow * 128 + aslt * 16);
                int brow = wc * 64 + t * 16 + l15;
                int bslt = (ks * 4 + kg) ^ (brow & 7);
                bfr[t] = *(const bf16x8*)((const char*)Bs + brow * 128 + bslt * 16);
            }
            #pragma unroll
            for (int mi = 0; mi < 4; ++mi)
                #pragma unroll
                for (int ni = 0; ni < 4; ++ni)
                    acc[mi][ni] = __builtin_amdgcn_mfma_f32_16x16x32_bf16(
                        af[mi], bfr[ni], acc[mi][ni], 0, 0, 0);
        }
    }

    // epilogue: C/D layout col=lane&15, row=(lane>>4)*4+reg (m89-verified)
    #pragma unroll
    for (int ni = 0; ni < 4; ++ni) {
        int colW = NT0 + wc * 64 + ni * 16 + l15;
        float bv = bias[colW];
        #pragma unroll
        for (int mi = 0; mi < 4; ++mi) {
            #pragma unroll
            for (int r = 0; r < 4; ++r) {
                float v = acc[mi][ni][r] + bv;
                int grow = R0 + wr * 64 + mi * 16 + kg * 4 + r;
                if (MODE == 0) {
                    ((ushort*)Cout)[(size_t)grow * 256 + colW] = f2b(v);
                } else if (MODE == 1) {
                    if (grow < M)
                        ((float*)Cout)[(size_t)grow * 512 + (colW - 256)] = v;
                } else {
                    ((float*)Cout)[(size_t)grow * 256 + colW] = v;
                }
            }
        }
    }
}

__global__ __launch_bounds__(256) void k_gemm_qkv(
    const ushort* __restrict__ xb, const ushort* __restrict__ wqT,
    const float* __restrict__ b, ushort* __restrict__ qb,
    float* __restrict__ kv)
{
    __shared__ ushort As[128 * 64];
    __shared__ ushort Bs[128 * 64];
    int bx = blockIdx.x;
    if (bx < 392) {   // Q: 196 mt x 2 nt, cols 0..255 -> bf16 qbuf
        mfma_tile<0>(xb, MROWS, wqT, b, qb, (bx >> 1) * 128, (bx & 1) * 128, As, Bs);
    } else {          // KV: 13 mt x 4 nt, cols 256..767 -> f32 kvbuf
        int b2 = bx - 392;
        mfma_tile<1>(xb, KVROWS, wqT, b, kv, (b2 >> 2) * 128, 256 + (b2 & 3) * 128, As, Bs);
    }
}

__global__ __launch_bounds__(256) void k_gemm_proj(
    const ushort* __restrict__ ob, const ushort* __restrict__ wpT,
    const float* __restrict__ b, float* __restrict__ out)
{
    __shared__ ushort As[128 * 64];
    __shared__ ushort Bs[128 * 64];
    mfma_tile<2>(ob, MROWS, wpT, b, out, (blockIdx.x >> 1) * 128,
                 (blockIdx.x & 1) * 128, As, Bs);
}

// ---------------------------------------------------------------------------
// Attention: (kv,h,wg) blocks, K/V/bias in LDS, streaming no-max exp2 softmax.
// Round-4 lesson: compiler targeted 8 waves/EU, shrank to 64 arch VGPR and
// shuffled ~50 live floats through AGPRs (~2x VALU). waves_per_eu(4,4) pins
// the budget at 128 so live state (~115) stays in arch VGPRs.
// ---------------------------------------------------------------------------
__global__ __launch_bounds__(256)
__attribute__((amdgpu_waves_per_eu(4, 4)))
void k_attn(
    const ushort* __restrict__ qb,    // (25088, 256) bf16
    const float* __restrict__ kvbuf,  // (1568, 512) f32: K | V
    const float* __restrict__ table,  // (169, 8)
    ushort* __restrict__ obuf)        // (25088, 256) bf16
{
    __shared__ float Ks[49 * 32];
    __shared__ float Vs[49 * 32];
    __shared__ float Bsh[49 * 49];

    const int kv  = blockIdx.x;
    const int h   = blockIdx.y;
    const int wg  = blockIdx.z;
    const int tid = threadIdx.x;

    const float* kvb = kvbuf + (size_t)(kv * 49) * 512 + h * 32;
    for (int idx = tid; idx < 392; idx += 256) {
        int row = idx >> 3, q4 = idx & 7;
        const float* src = kvb + row * 512 + q4 * 4;
        ((float4*)Ks)[idx] = *(const float4*)src;
        ((float4*)Vs)[idx] = *(const float4*)(src + 256);
    }
    for (int idx = tid; idx < 2401; idx += 256) {
        int r = idx / 49, j = idx - r * 49;
        int rh = r / 7, rw = r - rh * 7;
        int jh = j / 7, jw = j - jh * 7;
        int t = ((rh - jh + 6) * 13 + (rw - jw + 6)) * HEADS + h;
        Bsh[idx] = table[t] * LOG2E;
    }
    __syncthreads();

    const int lane = tid & 63;
    const int wi   = tid >> 6;
    const int w    = wg * 4 + wi;
    const int m    = kv + 32 * w;
    const int r    = lane < 49 ? lane : 48;
    const float* brow = Bsh + r * 49;

    float o_tot[32];
    #pragma unroll
    for (int d = 0; d < 32; ++d) o_tot[d] = 0.f;

    for (int tt = 0; tt < 4; ++tt) {
        const int qidx = tt * 128 + (m >> 2);
        const ushort* qp = qb + ((size_t)qidx * 49 + r) * 256 + h * 32;
        float q[32];
        #pragma unroll
        for (int g = 0; g < 4; ++g) {
            uint4 u = *(const uint4*)(qp + g * 8);
            uint uu[4] = {u.x, u.y, u.z, u.w};
            #pragma unroll
            for (int p = 0; p < 4; ++p) {
                q[g*8 + 2*p]     = __uint_as_float(uu[p] << 16) * SCALE_L2;
                q[g*8 + 2*p + 1] = __uint_as_float(uu[p] & 0xffff0000u) * SCALE_L2;
            }
        }

        float o_tt[32];
        #pragma unroll
        for (int d = 0; d < 32; ++d) o_tt[d] = 0.f;
        float sum = 0.f;

        #pragma unroll 7
        for (int j = 0; j < 49; ++j) {
            const float* kp = Ks + j * 32;        // wave-uniform LDS broadcast
            float a0 = 0.f, a1 = 0.f, a2 = 0.f, a3 = 0.f;
            #pragma unroll
            for (int d4 = 0; d4 < 8; ++d4) {
                float4 k4 = *(const float4*)(kp + d4 * 4);
                a0 = fmaf(q[d4*4+0], k4.x, a0);
                a1 = fmaf(q[d4*4+1], k4.y, a1);
                a2 = fmaf(q[d4*4+2], k4.z, a2);
                a3 = fmaf(q[d4*4+3], k4.w, a3);
            }
            const float e = exp2f((a0 + a1) + (a2 + a3) + brow[j]);
            sum += e;

            const float* vp = Vs + j * 32;
            #pragma unroll
            for (int d4 = 0; d4 < 8; ++d4) {
                float4 v4 = *(const float4*)(vp + d4 * 4);
                o_tt[d4*4+0] = fmaf(e, v4.x, o_tt[d4*4+0]);
                o_tt[d4*4+1] = fmaf(e, v4.y, o_tt[d4*4+1]);
                o_tt[d4*4+2] = fmaf(e, v4.z, o_tt[d4*4+2]);
                o_tt[d4*4+3] = fmaf(e, v4.w, o_tt[d4*4+3]);
            }
        }

        const float inv = 1.0f / sum;
        #pragma unroll
        for (int d = 0; d < 32; ++d) o_tot[d] = fmaf(o_tt[d], inv, o_tot[d]);
    }

    if (lane < 49) {
        ushort* op = obuf + ((size_t)m * 49 + lane) * 256 + h * 32;
        #pragma unroll
        for (int g = 0; g < 4; ++g) {
            uint4 pkd;
            uint* pu = (uint*)&pkd;
            #pragma unroll
            for (int p = 0; p < 4; ++p) {
                uint lo = f2b(o_tot[g*8 + 2*p]     * 0.25f);
                uint hi = f2b(o_tot[g*8 + 2*p + 1] * 0.25f);
                pu[p] = lo | (hi << 16);
            }
            *(uint4*)(op + g * 8) = pkd;
        }
    }
}

// ---------------------------------------------------------------------------
extern "C" void kernel_launch(void* const* d_in, const int* in_sizes, int n_in,
                              void* d_out, int out_size, void* d_ws, size_t ws_size,
                              hipStream_t stream)
{
    const float* x      = (const float*)d_in[0];
    const float* w_qkv  = (const float*)d_in[1];
    const float* b_qkv  = (const float*)d_in[2];
    const float* table  = (const float*)d_in[3];
    const float* w_proj = (const float*)d_in[4];
    const float* b_proj = (const float*)d_in[5];
    float* out = (float*)d_out;

    // ws layout (42.3 MB total):
    char* p = (char*)d_ws;
    ushort* qb  = (ushort*)p;                 p += (size_t)MROWS * 256 * 2;   // 12.85 MB
    float*  kvb = (float*)p;                  p += (size_t)KVROWS * 512 * 4;  //  3.21 MB
    ushort* ob  = (ushort*)p;                 p += (size_t)MROWS * 256 * 2;   // 12.85 MB
    ushort* xb  = (ushort*)p;                 p += (size_t)MROWS * 256 * 2;   // 12.85 MB
    ushort* wqT = (ushort*)p;                 p += (size_t)768 * 256 * 2;     //  0.39 MB
    ushort* wpT = (ushort*)p;

    k_prep<<<7296, 256, 0, stream>>>(x, w_qkv, w_proj, xb, wqT, wpT);
    k_gemm_qkv<<<444, 256, 0, stream>>>(xb, wqT, b_qkv, qb, kvb);
    k_attn<<<dim3(32, 8, 4), 256, 0, stream>>>(qb, kvb, table, ob);
    k_gemm_proj<<<392, 256, 0, stream>>>(ob, wpT, b_proj, out);
}